// Round 12
// baseline (379.302 us; speedup 1.0000x reference)
//
#include <hip/hip_runtime.h>
#include <hip/hip_cooperative_groups.h>

namespace cg = cooperative_groups;

#define HID 64
#define TT  128
#define NROWS 8192
#define NGRP (NROWS / 16)   // 512 groups; grid == co-residency capacity (2/CU)
#define LOG2E 1.44269504088896f

typedef _Float16 half8 __attribute__((ext_vector_type(8)));
typedef float    f32x4 __attribute__((ext_vector_type(4)));

// d_ws byte layout
#define WS_WF    0        // 12 tiles * 64 lanes * 8 f16
#define WS_WHH   12288    // 12 * 2kt * 64 * 8 f16
#define WS_BA    36864    // 128 f32 fused bias r,z (log2e-scaled)
#define WS_BX    37376    // 64 f32 b_f n-side (2log2e-scaled)
#define WS_BH    37632    // 64 f32 b_hh n-side (2log2e-scaled)
#define WS_EMB   37888    // 17*8 f16 embedding rows
#define WS_LROW  38176    // 8192 i32 per-row length
#define WS_ORDER 70944    // 8192 i32 rows sorted ascending by (L, idx)

// Single cooperative dispatch; phases separated by grid.sync().
// Phase A: per-block row lengths + (blocks 0..2) weight fusion/tiles/emb.
// Phase B: exact sort positions by counting (no atomics, no histogram).
// Phase C: R11's measured-best GRU step loop on sorted, paired groups.
__global__ __launch_bounds__(256, 2) void gru_all(
    const int* __restrict__ actor_ids, const int* __restrict__ action_ids,
    const int* __restrict__ street_ids, const float* __restrict__ bet,
    const int* __restrict__ mask,
    const float* __restrict__ E_actor, const float* __restrict__ E_action,
    const float* __restrict__ E_street, const float* __restrict__ W_proj,
    const float* __restrict__ b_proj, const float* __restrict__ W_ih,
    const float* __restrict__ b_ih, const float* __restrict__ W_hh,
    const float* __restrict__ b_hh,
    char* __restrict__ ws, float* __restrict__ out)
{
    cg::grid_group grid = cg::this_grid();

    _Float16* WF  = (_Float16*)(ws + WS_WF);
    _Float16* WHH = (_Float16*)(ws + WS_WHH);
    float*    BA  = (float*)(ws + WS_BA);
    float*    BX  = (float*)(ws + WS_BX);
    float*    BH  = (float*)(ws + WS_BH);
    _Float16* EMB = (_Float16*)(ws + WS_EMB);
    int*      Lrow  = (int*)(ws + WS_LROW);
    int*      order = (int*)(ws + WS_ORDER);

    // phase-aliased LDS arena:
    //  A: part[16][16] int (1 KB)   | block0: wfs[192][32] f32 (24.6 KB)
    //  B: Lds[2048] int (8 KB) + pB[16][16] int @8192
    //  C: pb[128][17] int (8.7 KB) + hb[2][16][72] f16 @8704 (4.6 KB)
    __shared__ __align__(16) char arena[25728];
    __shared__ __align__(16) _Float16 embl[144];

    const int tid = threadIdx.x;
    const int b   = blockIdx.x;

    // ---------------- Phase A: lengths ----------------
    {
        int* part = (int*)arena;
        const int r = tid >> 4, tl = tid & 15;
        const int base = (b * 16 + r) * TT;
        int cnt = 0;
        #pragma unroll
        for (int i = 0; i < 8; i++) cnt += (mask[base + tl + 16 * i] != 0);
        part[r * 16 + tl] = cnt;
        __syncthreads();
        if (tid < 16) {
            int L = 0;
            #pragma unroll
            for (int i = 0; i < 16; i++) L += part[tid * 16 + i];
            Lrow[b * 16 + tid] = L;
        }
        __syncthreads();   // part dead; block 0 may reuse arena as wfs
    }

    // ------------- weight prep (blocks 0..2, overlapped) -------------
    if (b == 0) {
        float* wfs = (float*)arena;   // [192][32]
        const int j = tid;
        if (j < 192) {
            float wf[21];
            #pragma unroll
            for (int m = 0; m < 21; m++) wf[m] = 0.f;
            float bf = b_ih[j];
            for (int k = 0; k < 32; k++) {
                float w = W_ih[j * 32 + k];
                bf += w * b_proj[k];
                #pragma unroll
                for (int m = 0; m < 21; m++) wf[m] += w * W_proj[k * 21 + m];
            }
            const float s = (j < 128) ? LOG2E : 2.f * LOG2E;
            #pragma unroll
            for (int m = 0; m < 21; m++) wfs[j * 32 + m] = wf[m] * s;
            #pragma unroll
            for (int m = 21; m < 32; m++) wfs[j * 32 + m] = 0.f;
            if (j < 128) BA[j] = (bf + b_hh[j]) * LOG2E;
            else { BX[j - 128] = bf * 2.f * LOG2E; BH[j - 128] = b_hh[j] * 2.f * LOG2E; }
        }
        __syncthreads();
        // WF A-layout: A[m=lane&15][k=(lane>>4)*8+pos]
        for (int idx = tid; idx < 12 * 64; idx += 256) {
            const int T = idx >> 6, lane = idx & 63;
            const int g3 = T >> 2, w = T & 3, m16 = lane & 15, kq = lane >> 4;
            const int jr = g3 * 64 + w * 16 + m16;
            _Float16 v[8];
            #pragma unroll
            for (int m = 0; m < 8; m++) v[m] = (_Float16)wfs[jr * 32 + kq * 8 + m];
            *(uint4*)&WF[idx * 8] = *(uint4*)v;
        }
    } else if (b == 1) {
        for (int idx = tid; idx < 12 * 2 * 64; idx += 256) {
            const int T = idx >> 7, rem = idx & 127, kt = rem >> 6, lane = rem & 63;
            const int g3 = T >> 2, w = T & 3, m16 = lane & 15, kq = lane >> 4;
            const int jr = g3 * 64 + w * 16 + m16;
            const int kbase = kt * 32 + kq * 8;
            const float s = (jr < 128) ? LOG2E : 2.f * LOG2E;
            _Float16 v[8];
            #pragma unroll
            for (int m = 0; m < 8; m++) v[m] = (_Float16)(W_hh[jr * HID + kbase + m] * s);
            *(uint4*)&WHH[((T * 2 + kt) * 64 + lane) * 8] = *(uint4*)v;
        }
    } else if (b == 2) {
        if (tid < 17 * 8) {   // 0..6 actor, 7..10 action, 11..15 street, 16 zero
            int r = tid >> 3, m = tid & 7;
            float v = 0.f;
            if (r < 7)       v = E_actor[r * 8 + m];
            else if (r < 11) v = E_action[(r - 7) * 8 + m];
            else if (r < 16) v = (m < 4) ? E_street[(r - 11) * 4 + m] : 0.f;
            EMB[tid] = (_Float16)v;
        }
    }
    __threadfence();
    grid.sync();

    // ---------------- Phase B: sort positions by counting ----------------
    {
        int* Lds = (int*)arena;            // 2048 ints
        int* pB  = (int*)(arena + 8192);   // [16][16]
        const int j  = tid & 15, tp = tid >> 4;
        const int myr = b * 16 + j;
        const int Lj  = Lrow[myr];
        int cnt = 0;
        for (int c = 0; c < 4; c++) {
            for (int i = tid; i < 2048; i += 256) Lds[i] = Lrow[c * 2048 + i];
            __syncthreads();
            const int kb = c * 2048 + tp * 128;
            #pragma unroll 4
            for (int k = 0; k < 128; k++) {
                const int Lk = Lds[tp * 128 + k];
                const int kg = kb + k;
                cnt += (Lk < Lj) | ((Lk == Lj) & (kg < myr));
            }
            __syncthreads();
        }
        pB[j * 16 + tp] = cnt;
        __syncthreads();
        if (tid < 16) {
            int pos = 0;
            #pragma unroll
            for (int i = 0; i < 16; i++) pos += pB[tid * 16 + i];
            order[pos] = b * 16 + tid;
        }
    }
    __threadfence();
    grid.sync();

    // ---------------- Phase C: GRU (R11 measured-best loop) ----------------
    int*      pb = (int*)arena;                  // [TT][17]
    _Float16* hb = (_Float16*)(arena + 8704);    // [2][16][72]

    const int wv = tid >> 6;        // wave = hid quarter
    const int l  = tid & 63;
    const int q  = l >> 4;          // quad
    const int n  = l & 15;          // batch col within group

    const int g = (b & 1) ? (NGRP - 1 - (b >> 1)) : (b >> 1);   // long/short pairing

    for (int i = tid; i < 136; i += 256) embl[i] = EMB[i];
    for (int i = tid; i < 2 * 16 * 72 / 2; i += 256) ((int*)hb)[i] = 0;
    {   // stage packed ids+bet16: 16 thr/row, 8 t/thr
        const int r = tid >> 4, tl = tid & 15;
        const int rowr = order[g * 16 + r];
        const int base = rowr * TT;
        #pragma unroll
        for (int i = 0; i < 8; i++) {
            const int t = tl + 16 * i;
            const int a = actor_ids[base + t], c = action_ids[base + t];
            const int s = street_ids[base + t];
            const _Float16 f16 = (_Float16)bet[base + t];
            const unsigned fb = (unsigned)*(const unsigned short*)&f16;
            pb[t * 17 + r] = (int)(a | (c << 3) | (s << 5) | (fb << 16));
        }
    }

    // loop-invariant A-fragments (AGPR-resident is fine for MFMA operands)
    half8 Af[3], Ah[3][2];
    #pragma unroll
    for (int g3 = 0; g3 < 3; g3++) {
        const int T = g3 * 4 + wv;
        Af[g3]    = *(const half8*)&WF[(T * 64 + l) * 8];
        Ah[g3][0] = *(const half8*)&WHH[((T * 2 + 0) * 64 + l) * 8];
        Ah[g3][1] = *(const half8*)&WHH[((T * 2 + 1) * 64 + l) * 8];
    }
    f32x4 biasR, biasZ, biasX, biasH;
    #pragma unroll
    for (int e = 0; e < 4; e++) {
        const int idx = 16 * wv + 4 * q + e;
        biasR[e] = BA[idx];
        biasZ[e] = BA[64 + idx];
        biasX[e] = BX[idx];
        biasH[e] = BH[idx];
    }

    const int myrow = order[g * 16 + n];
    const int Ln    = Lrow[myrow];
    const int Lmax  = __shfl(Ln, 15);   // ascending sort -> n=15 holds max
    const bool isq2 = (q == 2);
    const int sh = (q == 1) ? 3 : (q == 2) ? 5 : 0;
    const int mk = (q == 1) ? 3 : (q == 3) ? 0 : 7;
    const int of = (q == 1) ? 7 : (q == 2) ? 11 : (q == 3) ? 16 : 0;

    float h[4] = {0.f, 0.f, 0.f, 0.f};

    __syncthreads();   // pb/hb/embl visible

    // prime step-0 x-side accumulators
    f32x4 xR, xZ, xX;
    {
        const int p = pb[0 * 17 + n];
        const int eidx = ((p >> sh) & mk) + of;
        half8 Bf = *(const half8*)&embl[eidx * 8];
        uint4* bu = (uint4*)&Bf;
        bu->z = isq2 ? ((unsigned)p >> 16) : bu->z;   // {bet16, 0} at k=20,21
        xR = __builtin_amdgcn_mfma_f32_16x16x32_f16(Af[0], Bf, biasR, 0, 0, 0);
        xZ = __builtin_amdgcn_mfma_f32_16x16x32_f16(Af[1], Bf, biasZ, 0, 0, 0);
        xX = __builtin_amdgcn_mfma_f32_16x16x32_f16(Af[2], Bf, biasX, 0, 0, 0);
    }

    for (int t = 0; t < Lmax; t++) {
        const int buf = t & 1;
        const half8 Bh0 = *(const half8*)&hb[(buf * 16 + n) * 72 + q * 8];
        const half8 Bh1 = *(const half8*)&hb[(buf * 16 + n) * 72 + 32 + q * 8];
        // K-tiles chained through the C operand (3 independent depth-2 chains)
        f32x4 aR = __builtin_amdgcn_mfma_f32_16x16x32_f16(Ah[0][0], Bh0, xR, 0, 0, 0);
        aR = __builtin_amdgcn_mfma_f32_16x16x32_f16(Ah[0][1], Bh1, aR, 0, 0, 0);
        f32x4 aZ = __builtin_amdgcn_mfma_f32_16x16x32_f16(Ah[1][0], Bh0, xZ, 0, 0, 0);
        aZ = __builtin_amdgcn_mfma_f32_16x16x32_f16(Ah[1][1], Bh1, aZ, 0, 0, 0);
        f32x4 aH = __builtin_amdgcn_mfma_f32_16x16x32_f16(Ah[2][0], Bh0, biasH, 0, 0, 0);
        aH = __builtin_amdgcn_mfma_f32_16x16x32_f16(Ah[2][1], Bh1, aH, 0, 0, 0);
        const f32x4 aXc = xX;

        // prefetch step t+1 x-side (independent of this step's h)
        {
            const int tn = (t + 1 < TT) ? t + 1 : TT - 1;
            const int p = pb[tn * 17 + n];
            const int eidx = ((p >> sh) & mk) + of;
            half8 Bf = *(const half8*)&embl[eidx * 8];
            uint4* bu = (uint4*)&Bf;
            bu->z = isq2 ? ((unsigned)p >> 16) : bu->z;
            xR = __builtin_amdgcn_mfma_f32_16x16x32_f16(Af[0], Bf, biasR, 0, 0, 0);
            xZ = __builtin_amdgcn_mfma_f32_16x16x32_f16(Af[1], Bf, biasZ, 0, 0, 0);
            xX = __builtin_amdgcn_mfma_f32_16x16x32_f16(Af[2], Bf, biasX, 0, 0, 0);
        }

        const bool live = (t < Ln);
        _Float16 hp[4];
        #pragma unroll
        for (int e = 0; e < 4; e++) {
            // weights pre-scaled: aR,aZ in log2 domain; aX,aH in 2log2e domain
            const float r = __builtin_amdgcn_rcpf(1.f + __builtin_amdgcn_exp2f(-aR[e]));
            const float z = __builtin_amdgcn_rcpf(1.f + __builtin_amdgcn_exp2f(-aZ[e]));
            const float y2 = aXc[e] + r * aH[e];           // = 2*log2e*y
            const float nn = 1.f - 2.f * __builtin_amdgcn_rcpf(1.f + __builtin_amdgcn_exp2f(y2));
            const float hv = nn + z * (h[e] - nn);
            h[e] = live ? hv : h[e];
            hp[e] = (_Float16)h[e];
        }
        *(uint2*)&hb[((buf ^ 1) * 16 + n) * 72 + 16 * wv + 4 * q] = *(uint2*)hp;
        __syncthreads();
    }

    float4 o = make_float4(h[0], h[1], h[2], h[3]);
    *(float4*)&out[myrow * HID + 16 * wv + 4 * q] = o;
}

extern "C" void kernel_launch(void* const* d_in, const int* in_sizes, int n_in,
                              void* d_out, int out_size, void* d_ws, size_t ws_size,
                              hipStream_t stream) {
    const int*   actor_ids  = (const int*)d_in[0];
    const int*   action_ids = (const int*)d_in[1];
    const int*   street_ids = (const int*)d_in[2];
    const float* bet        = (const float*)d_in[3];
    const int*   vmask      = (const int*)d_in[4];
    const float* E_actor    = (const float*)d_in[5];
    const float* E_action   = (const float*)d_in[6];
    const float* E_street   = (const float*)d_in[7];
    const float* W_proj     = (const float*)d_in[8];
    const float* b_proj     = (const float*)d_in[9];
    const float* W_ih       = (const float*)d_in[10];
    const float* b_ih       = (const float*)d_in[12];
    const float* W_hh       = (const float*)d_in[11];
    const float* b_hh       = (const float*)d_in[13];
    float*       out        = (float*)d_out;
    char*        ws         = (char*)d_ws;

    void* args[] = {
        (void*)&actor_ids, (void*)&action_ids, (void*)&street_ids, (void*)&bet,
        (void*)&vmask, (void*)&E_actor, (void*)&E_action, (void*)&E_street,
        (void*)&W_proj, (void*)&b_proj, (void*)&W_ih, (void*)&b_ih,
        (void*)&W_hh, (void*)&b_hh, (void*)&ws, (void*)&out
    };
    hipLaunchCooperativeKernel((const void*)gru_all, dim3(NGRP), dim3(256),
                               args, 0, stream);
}

// Round 13
// 181.903 us; speedup vs baseline: 2.0852x; 2.0852x over previous
//
#include <hip/hip_runtime.h>

#define HID 64
#define TT  128
#define NROWS 8192
#define NGRP (NROWS / 16)   // 512 groups of 16 length-sorted rows
#define LOG2E 1.44269504088896f

typedef _Float16 half8 __attribute__((ext_vector_type(8)));
typedef float    f32x4 __attribute__((ext_vector_type(4)));

// d_ws byte layout
#define WS_WF    0        // 12 tiles * 64 lanes * 8 f16  = 12288 B
#define WS_WHH   12288    // 12 * 2kt * 64 * 8 f16        = 24576 B
#define WS_BA    36864    // 128 f32 fused bias r,z (log2e-scaled)
#define WS_BX    37376    // 64 f32 b_f n-side (2log2e-scaled)
#define WS_BH    37632    // 64 f32 b_hh n-side (2log2e-scaled)
#define WS_EMB   37888    // 17*8 f16 embedding rows
#define WS_LROW  38176    // 8192 i32 per-row length
#define WS_ORDER 70944    // 8192 i32 rows sorted ascending by (L, idx)

// blocks 0..63: per-row lengths (ballot popcount). block 64: weight fusion +
// MFMA A-tile emission + emb table.
__global__ __launch_bounds__(256) void prep(
    const float* __restrict__ E_actor, const float* __restrict__ E_action,
    const float* __restrict__ E_street, const float* __restrict__ W_proj,
    const float* __restrict__ b_proj, const float* __restrict__ W_ih,
    const float* __restrict__ b_ih, const float* __restrict__ W_hh,
    const float* __restrict__ b_hh, const int* __restrict__ mask,
    char* __restrict__ ws)
{
    const int j = threadIdx.x;
    if (blockIdx.x != 64) {
        int* Lrow = (int*)(ws + WS_LROW);
        const int wv = j >> 6, ln = j & 63;
        const int r0 = blockIdx.x * 128;
        for (int i = 0; i < 32; i++) {
            const int row = r0 + i * 4 + wv, base = row * TT;
            const int m0 = mask[base + ln], m1 = mask[base + 64 + ln];
            const int L = __popcll(__ballot(m0 != 0)) + __popcll(__ballot(m1 != 0));
            if (ln == 0) Lrow[row] = L;
        }
        return;
    }

    _Float16* WF  = (_Float16*)(ws + WS_WF);
    _Float16* WHH = (_Float16*)(ws + WS_WHH);
    float*    BA  = (float*)(ws + WS_BA);
    float*    BX  = (float*)(ws + WS_BX);
    float*    BH  = (float*)(ws + WS_BH);
    _Float16* EMB = (_Float16*)(ws + WS_EMB);

    __shared__ float wfs[192][32];
    if (j < 192) {
        // W_f[j][m] = sum_k W_ih[j,k]*W_proj[k,m]; b_f = b_ih + W_ih*b_proj
        float wf[21];
        #pragma unroll
        for (int m = 0; m < 21; m++) wf[m] = 0.f;
        float bf = b_ih[j];
        for (int k = 0; k < 32; k++) {
            float w = W_ih[j * 32 + k];
            bf += w * b_proj[k];
            #pragma unroll
            for (int m = 0; m < 21; m++) wf[m] += w * W_proj[k * 21 + m];
        }
        // fold log2e (r,z rows) / 2log2e (n rows): activations become raw exp2
        const float s = (j < 128) ? LOG2E : 2.f * LOG2E;
        #pragma unroll
        for (int m = 0; m < 21; m++) wfs[j][m] = wf[m] * s;
        #pragma unroll
        for (int m = 21; m < 32; m++) wfs[j][m] = 0.f;
        if (j < 128) BA[j] = (bf + b_hh[j]) * LOG2E;
        else { BX[j - 128] = bf * 2.f * LOG2E; BH[j - 128] = b_hh[j] * 2.f * LOG2E; }
    }
    if (j < 17 * 8) {   // emb rows: 0..6 actor, 7..10 action, 11..15 street, 16 zero
        int r = j >> 3, m = j & 7;
        float v = 0.f;
        if (r < 7)       v = E_actor[r * 8 + m];
        else if (r < 11) v = E_action[(r - 7) * 8 + m];
        else if (r < 16) v = (m < 4) ? E_street[(r - 11) * 4 + m] : 0.f;
        EMB[j] = (_Float16)v;
    }
    __syncthreads();

    // A-layout: A[m=lane&15][k=(lane>>4)*8+pos]
    for (int idx = j; idx < 12 * 64; idx += 256) {
        const int T = idx >> 6, lane = idx & 63;
        const int g3 = T >> 2, w = T & 3, m16 = lane & 15, kq = lane >> 4;
        const int jr = g3 * 64 + w * 16 + m16;
        _Float16 v[8];
        #pragma unroll
        for (int m = 0; m < 8; m++) v[m] = (_Float16)wfs[jr][kq * 8 + m];
        *(uint4*)&WF[idx * 8] = *(uint4*)v;
    }
    for (int idx = j; idx < 12 * 2 * 64; idx += 256) {
        const int T = idx >> 7, rem = idx & 127, kt = rem >> 6, lane = rem & 63;
        const int g3 = T >> 2, w = T & 3, m16 = lane & 15, kq = lane >> 4;
        const int jr = g3 * 64 + w * 16 + m16;
        const int kbase = kt * 32 + kq * 8;
        const float s = (jr < 128) ? LOG2E : 2.f * LOG2E;
        _Float16 v[8];
        #pragma unroll
        for (int m = 0; m < 8; m++) v[m] = (_Float16)(W_hh[jr * HID + kbase + m] * s);
        *(uint4*)&WHH[((T * 2 + kt) * 64 + lane) * 8] = *(uint4*)v;
    }
}

// 512 blocks: exact sorted position of each of the block's 16 rows by
// counting (L<Lj)|(L==Lj & idx<myr) over all 8192 lengths, LDS-staged in 4
// chunks. 16 threads/row, 512 entries each. No atomics, no serial scan.
// (Ran correctly as R12 phase B; extracted because grid.sync cost ~100us.)
__global__ __launch_bounds__(256) void psort(
    const int* __restrict__ Lrow, int* __restrict__ order)
{
    __shared__ int Lds[2048];
    __shared__ int pB[16][16];
    const int tid = threadIdx.x;
    const int b   = blockIdx.x;
    const int j = tid & 15, tp = tid >> 4;
    const int myr = b * 16 + j;
    const int Lj  = Lrow[myr];
    int cnt = 0;
    for (int c = 0; c < 4; c++) {
        for (int i = tid; i < 2048; i += 256) Lds[i] = Lrow[c * 2048 + i];
        __syncthreads();
        const int kb = c * 2048 + tp * 128;
        #pragma unroll 4
        for (int k = 0; k < 128; k++) {
            const int Lk = Lds[tp * 128 + k];
            const int kg = kb + k;
            cnt += (Lk < Lj) | ((Lk == Lj) & (kg < myr));
        }
        __syncthreads();
    }
    pB[j][tp] = cnt;
    __syncthreads();
    if (tid < 16) {
        int pos = 0;
        #pragma unroll
        for (int i = 0; i < 16; i++) pos += pB[tid][i];
        order[pos] = b * 16 + tid;
    }
}

// One 256-thread block (4 waves) per 16-row length-sorted group; wave wv owns
// hid quarter [16wv,16wv+16) = M-tiles {wv,4+wv,8+wv}. Per step: 6 h-side
// MFMA (K-tiles chained through C) + 3 x-side MFMA prefetched for t+1.
// Weights pre-scaled by log2e/2log2e -> raw exp2 activations. fp32 h master
// in regs, f16 LDS copy double-buffered. (Bit-identical to R11's 66.9us best.)
__global__ __launch_bounds__(256, 2) void gru_mfma(
    const int* __restrict__ actor_ids, const int* __restrict__ action_ids,
    const int* __restrict__ street_ids, const float* __restrict__ bet,
    const char* __restrict__ ws, const int* __restrict__ order,
    const int* __restrict__ Lrow, float* __restrict__ out)
{
    const _Float16* WF  = (const _Float16*)(ws + WS_WF);
    const _Float16* WHH = (const _Float16*)(ws + WS_WHH);
    const float*    BA  = (const float*)(ws + WS_BA);
    const float*    BX  = (const float*)(ws + WS_BX);
    const float*    BH  = (const float*)(ws + WS_BH);
    const _Float16* EMB = (const _Float16*)(ws + WS_EMB);

    __shared__ int pb[TT][17];                        // ids|bet16, padded
    __shared__ __align__(16) _Float16 hb[2][16][72];  // stride 72: 2-way max (free)
    __shared__ __align__(16) _Float16 embl[144];

    const int tid = threadIdx.x;
    const int wv  = tid >> 6;        // wave = hid quarter
    const int l   = tid & 63;
    const int q   = l >> 4;          // quad
    const int n   = l & 15;          // batch col within group

    const int b = blockIdx.x;
    const int g = (b & 1) ? (NGRP - 1 - (b >> 1)) : (b >> 1);

    for (int i = tid; i < 136; i += 256) embl[i] = EMB[i];
    for (int i = tid; i < 2 * 16 * 72 / 2; i += 256) ((int*)hb)[i] = 0;
    {   // stage packed ids+bet16: 16 thr/row, 8 t/thr
        const int r = tid >> 4, tl = tid & 15;
        const int rowr = order[g * 16 + r];
        const int base = rowr * TT;
        #pragma unroll
        for (int i = 0; i < 8; i++) {
            const int t = tl + 16 * i;
            const int a = actor_ids[base + t], c = action_ids[base + t];
            const int s = street_ids[base + t];
            const _Float16 f16 = (_Float16)bet[base + t];
            const unsigned fb = (unsigned)*(const unsigned short*)&f16;
            pb[t][r] = (int)(a | (c << 3) | (s << 5) | (fb << 16));
        }
    }

    // loop-invariant A-fragments (AGPR-resident is fine for MFMA operands)
    half8 Af[3], Ah[3][2];
    #pragma unroll
    for (int g3 = 0; g3 < 3; g3++) {
        const int T = g3 * 4 + wv;
        Af[g3]    = *(const half8*)&WF[(T * 64 + l) * 8];
        Ah[g3][0] = *(const half8*)&WHH[((T * 2 + 0) * 64 + l) * 8];
        Ah[g3][1] = *(const half8*)&WHH[((T * 2 + 1) * 64 + l) * 8];
    }
    f32x4 biasR, biasZ, biasX, biasH;
    #pragma unroll
    for (int e = 0; e < 4; e++) {
        const int idx = 16 * wv + 4 * q + e;
        biasR[e] = BA[idx];
        biasZ[e] = BA[64 + idx];
        biasX[e] = BX[idx];
        biasH[e] = BH[idx];
    }

    const int myrow = order[g * 16 + n];
    const int Ln    = Lrow[myrow];
    const int Lmax  = __shfl(Ln, 15);   // ascending sort -> n=15 holds max
    const bool isq2 = (q == 2);
    const int sh = (q == 1) ? 3 : (q == 2) ? 5 : 0;
    const int mk = (q == 1) ? 3 : (q == 3) ? 0 : 7;
    const int of = (q == 1) ? 7 : (q == 2) ? 11 : (q == 3) ? 16 : 0;

    float h[4] = {0.f, 0.f, 0.f, 0.f};

    __syncthreads();   // pb/hb/embl visible

    // prime step-0 x-side accumulators
    f32x4 xR, xZ, xX;
    {
        const int p = pb[0][n];
        const int eidx = ((p >> sh) & mk) + of;
        half8 Bf = *(const half8*)&embl[eidx * 8];
        uint4* bu = (uint4*)&Bf;
        bu->z = isq2 ? ((unsigned)p >> 16) : bu->z;   // {bet16, 0} at k=20,21
        xR = __builtin_amdgcn_mfma_f32_16x16x32_f16(Af[0], Bf, biasR, 0, 0, 0);
        xZ = __builtin_amdgcn_mfma_f32_16x16x32_f16(Af[1], Bf, biasZ, 0, 0, 0);
        xX = __builtin_amdgcn_mfma_f32_16x16x32_f16(Af[2], Bf, biasX, 0, 0, 0);
    }

    for (int t = 0; t < Lmax; t++) {
        const int buf = t & 1;
        const half8 Bh0 = *(const half8*)&hb[buf][n][q * 8];
        const half8 Bh1 = *(const half8*)&hb[buf][n][32 + q * 8];
        // K-tiles chained through the C operand (3 independent depth-2 chains)
        f32x4 aR = __builtin_amdgcn_mfma_f32_16x16x32_f16(Ah[0][0], Bh0, xR, 0, 0, 0);
        aR = __builtin_amdgcn_mfma_f32_16x16x32_f16(Ah[0][1], Bh1, aR, 0, 0, 0);
        f32x4 aZ = __builtin_amdgcn_mfma_f32_16x16x32_f16(Ah[1][0], Bh0, xZ, 0, 0, 0);
        aZ = __builtin_amdgcn_mfma_f32_16x16x32_f16(Ah[1][1], Bh1, aZ, 0, 0, 0);
        f32x4 aH = __builtin_amdgcn_mfma_f32_16x16x32_f16(Ah[2][0], Bh0, biasH, 0, 0, 0);
        aH = __builtin_amdgcn_mfma_f32_16x16x32_f16(Ah[2][1], Bh1, aH, 0, 0, 0);
        const f32x4 aXc = xX;

        // prefetch step t+1 x-side (independent of this step's h)
        {
            const int tn = (t + 1 < TT) ? t + 1 : TT - 1;
            const int p = pb[tn][n];
            const int eidx = ((p >> sh) & mk) + of;
            half8 Bf = *(const half8*)&embl[eidx * 8];
            uint4* bu = (uint4*)&Bf;
            bu->z = isq2 ? ((unsigned)p >> 16) : bu->z;
            xR = __builtin_amdgcn_mfma_f32_16x16x32_f16(Af[0], Bf, biasR, 0, 0, 0);
            xZ = __builtin_amdgcn_mfma_f32_16x16x32_f16(Af[1], Bf, biasZ, 0, 0, 0);
            xX = __builtin_amdgcn_mfma_f32_16x16x32_f16(Af[2], Bf, biasX, 0, 0, 0);
        }

        const bool live = (t < Ln);
        _Float16 hp[4];
        #pragma unroll
        for (int e = 0; e < 4; e++) {
            // weights pre-scaled: aR,aZ in log2 domain; aX,aH in 2log2e domain
            const float r = __builtin_amdgcn_rcpf(1.f + __builtin_amdgcn_exp2f(-aR[e]));
            const float z = __builtin_amdgcn_rcpf(1.f + __builtin_amdgcn_exp2f(-aZ[e]));
            const float y2 = aXc[e] + r * aH[e];           // = 2*log2e*y
            const float nn = 1.f - 2.f * __builtin_amdgcn_rcpf(1.f + __builtin_amdgcn_exp2f(y2));
            const float hv = nn + z * (h[e] - nn);
            h[e] = live ? hv : h[e];
            hp[e] = (_Float16)h[e];
        }
        *(uint2*)&hb[buf ^ 1][n][16 * wv + 4 * q] = *(uint2*)hp;
        __syncthreads();
    }

    float4 o = make_float4(h[0], h[1], h[2], h[3]);
    *(float4*)&out[myrow * HID + 16 * wv + 4 * q] = o;
}

extern "C" void kernel_launch(void* const* d_in, const int* in_sizes, int n_in,
                              void* d_out, int out_size, void* d_ws, size_t ws_size,
                              hipStream_t stream) {
    const int*   actor_ids  = (const int*)d_in[0];
    const int*   action_ids = (const int*)d_in[1];
    const int*   street_ids = (const int*)d_in[2];
    const float* bet        = (const float*)d_in[3];
    const int*   vmask      = (const int*)d_in[4];
    const float* E_actor    = (const float*)d_in[5];
    const float* E_action   = (const float*)d_in[6];
    const float* E_street   = (const float*)d_in[7];
    const float* W_proj     = (const float*)d_in[8];
    const float* b_proj     = (const float*)d_in[9];
    const float* W_ih       = (const float*)d_in[10];
    const float* W_hh       = (const float*)d_in[11];
    const float* b_ih       = (const float*)d_in[12];
    const float* b_hh       = (const float*)d_in[13];
    float*       out        = (float*)d_out;

    char* ws = (char*)d_ws;
    int*  Lrow  = (int*)(ws + WS_LROW);
    int*  order = (int*)(ws + WS_ORDER);

    prep<<<65, 256, 0, stream>>>(E_actor, E_action, E_street, W_proj, b_proj,
                                 W_ih, b_ih, W_hh, b_hh, vmask, ws);
    psort<<<NGRP, 256, 0, stream>>>(Lrow, order);
    gru_mfma<<<NGRP, 256, 0, stream>>>(actor_ids, action_ids, street_ids, bet,
                                       ws, order, Lrow, out);
}

// Round 14
// 165.242 us; speedup vs baseline: 2.2954x; 1.1008x over previous
//
#include <hip/hip_runtime.h>

#define HID 64
#define TT  128
#define NROWS 8192
#define NGRP (NROWS / 16)   // 512 blocks of 16 rows; exactly 2 blocks/CU
#define LOG2E 1.44269504088896f

typedef _Float16 half8 __attribute__((ext_vector_type(8)));
typedef float    f32x4 __attribute__((ext_vector_type(4)));

// Single-dispatch GRU: per-block inline weight fusion (redundant but parallel
// and L2-hot), in-kernel row lengths, R11's measured-best step loop.
// LDS arena is phase-aliased: startup wfs[192][32] f32 -> main pb/hb/part.
__global__ __launch_bounds__(256, 2) void gru_fused(
    const int* __restrict__ actor_ids, const int* __restrict__ action_ids,
    const int* __restrict__ street_ids, const float* __restrict__ bet,
    const int* __restrict__ mask,
    const float* __restrict__ E_actor, const float* __restrict__ E_action,
    const float* __restrict__ E_street, const float* __restrict__ W_proj,
    const float* __restrict__ b_proj, const float* __restrict__ W_ih,
    const float* __restrict__ b_ih, const float* __restrict__ W_hh,
    const float* __restrict__ b_hh, float* __restrict__ out)
{
    __shared__ __align__(16) union {
        float wfs[192][32];                           // startup: fused W_f (scaled)
        struct {
            int pb[TT][17];                           // ids|bet16, padded
            __align__(16) _Float16 hb[2][16][72];     // h f16 dbuf, stride 72
            int part[16][16];                         // mask popcount partials
            int Lsh[16];
        } c;
    } A;
    __shared__ __align__(16) _Float16 embl[144];
    __shared__ float bfs[192];                        // raw fused bias b_f

    const int tid = threadIdx.x;
    const int wv  = tid >> 6;        // wave = hid quarter
    const int l   = tid & 63;
    const int q   = l >> 4;          // quad
    const int n   = l & 15;          // batch col within group
    const int g   = blockIdx.x;

    // embedding rows: 0..6 actor, 7..10 action, 11..15 street(+pad), 16 zero
    for (int i = tid; i < 136; i += 256) {
        int r = i >> 3, m = i & 7;
        float v = 0.f;
        if (r < 7)       v = E_actor[r * 8 + m];
        else if (r < 11) v = E_action[(r - 7) * 8 + m];
        else if (r < 16) v = (m < 4) ? E_street[(r - 11) * 4 + m] : 0.f;
        embl[i] = (_Float16)v;
    }

    // ---- startup: fused input weights into LDS ----
    // W_f[j][m] = sum_k W_ih[j,k]*W_proj[k,m]; b_f = b_ih + W_ih*b_proj.
    // W_proj/b_proj indices are tid-independent -> wave-uniform scalar loads.
    if (tid < 192) {
        const int j = tid;
        float wf[21];
        #pragma unroll
        for (int m = 0; m < 21; m++) wf[m] = 0.f;
        float bf = b_ih[j];
        for (int k = 0; k < 32; k++) {
            const float w = W_ih[j * 32 + k];
            bf += w * b_proj[k];
            #pragma unroll
            for (int m = 0; m < 21; m++) wf[m] += w * W_proj[k * 21 + m];
        }
        // fold log2e (r,z rows) / 2log2e (n rows): activations = raw exp2
        const float s = (j < 128) ? LOG2E : 2.f * LOG2E;
        #pragma unroll
        for (int m = 0; m < 21; m++) A.wfs[j][m] = wf[m] * s;
        #pragma unroll
        for (int m = 21; m < 32; m++) A.wfs[j][m] = 0.f;
        bfs[j] = bf;
    }
    __syncthreads();

    // ---- extract per-lane A-fragments + biases (registers) ----
    // A-layout: A[m=lane&15][k=(lane>>4)*8+pos]
    half8 Af[3], Ah[3][2];
    {
        const int m16 = l & 15, kq = l >> 4;
        #pragma unroll
        for (int g3 = 0; g3 < 3; g3++) {
            const int jr = g3 * 64 + wv * 16 + m16;
            _Float16 v[8];
            #pragma unroll
            for (int m = 0; m < 8; m++) v[m] = (_Float16)A.wfs[jr][kq * 8 + m];
            Af[g3] = *(half8*)v;
            const float s = (g3 < 2) ? LOG2E : 2.f * LOG2E;
            #pragma unroll
            for (int kt = 0; kt < 2; kt++) {
                _Float16 w[8];
                #pragma unroll
                for (int m = 0; m < 8; m++)
                    w[m] = (_Float16)(W_hh[jr * HID + kt * 32 + kq * 8 + m] * s);
                Ah[g3][kt] = *(half8*)w;
            }
        }
    }
    f32x4 biasR, biasZ, biasX, biasH;
    #pragma unroll
    for (int e = 0; e < 4; e++) {
        const int idx = 16 * wv + 4 * q + e;
        biasR[e] = (bfs[idx]      + b_hh[idx])      * LOG2E;
        biasZ[e] = (bfs[64 + idx] + b_hh[64 + idx]) * LOG2E;
        biasX[e] = bfs[128 + idx]  * (2.f * LOG2E);
        biasH[e] = b_hh[128 + idx] * (2.f * LOG2E);
    }
    __syncthreads();   // wfs dead; arena becomes pb/hb/part

    // ---- stage pb (+ mask popcount partials), zero hb ----
    for (int i = tid; i < 2 * 16 * 72 / 2; i += 256) ((int*)A.c.hb)[i] = 0;
    {
        const int r = tid >> 4, tl = tid & 15;
        const int base = (g * 16 + r) * TT;
        int cnt = 0;
        #pragma unroll
        for (int i = 0; i < 8; i++) {
            const int t = tl + 16 * i;
            const int a = actor_ids[base + t], c = action_ids[base + t];
            const int s = street_ids[base + t];
            const _Float16 f16 = (_Float16)bet[base + t];
            const unsigned fb = (unsigned)*(const unsigned short*)&f16;
            A.c.pb[t][r] = (int)(a | (c << 3) | (s << 5) | (fb << 16));
            cnt += (mask[base + t] != 0);
        }
        A.c.part[r][tl] = cnt;
    }
    __syncthreads();
    if (tid < 16) {
        int L = 0;
        #pragma unroll
        for (int i = 0; i < 16; i++) L += A.c.part[tid][i];
        A.c.Lsh[tid] = L;
    }
    __syncthreads();

    const int Ln = A.c.Lsh[n];
    int Lmax = Ln;     // butterfly max over the 16 n-columns (wave-uniform)
    #pragma unroll
    for (int k = 1; k < 16; k <<= 1) {
        const int o = __shfl_xor(Lmax, k);
        Lmax = (o > Lmax) ? o : Lmax;
    }

    const bool isq2 = (q == 2);
    const int sh = (q == 1) ? 3 : (q == 2) ? 5 : 0;
    const int mk = (q == 1) ? 3 : (q == 3) ? 0 : 7;
    const int of = (q == 1) ? 7 : (q == 2) ? 11 : (q == 3) ? 16 : 0;

    float h[4] = {0.f, 0.f, 0.f, 0.f};

    // prime step-0 x-side accumulators
    f32x4 xR, xZ, xX;
    {
        const int p = A.c.pb[0][n];
        const int eidx = ((p >> sh) & mk) + of;
        half8 Bf = *(const half8*)&embl[eidx * 8];
        uint4* bu = (uint4*)&Bf;
        bu->z = isq2 ? ((unsigned)p >> 16) : bu->z;   // {bet16, 0} at k=20,21
        xR = __builtin_amdgcn_mfma_f32_16x16x32_f16(Af[0], Bf, biasR, 0, 0, 0);
        xZ = __builtin_amdgcn_mfma_f32_16x16x32_f16(Af[1], Bf, biasZ, 0, 0, 0);
        xX = __builtin_amdgcn_mfma_f32_16x16x32_f16(Af[2], Bf, biasX, 0, 0, 0);
    }

    for (int t = 0; t < Lmax; t++) {
        const int buf = t & 1;
        const half8 Bh0 = *(const half8*)&A.c.hb[buf][n][q * 8];
        const half8 Bh1 = *(const half8*)&A.c.hb[buf][n][32 + q * 8];
        // K-tiles chained through the C operand (3 independent depth-2 chains)
        f32x4 aR = __builtin_amdgcn_mfma_f32_16x16x32_f16(Ah[0][0], Bh0, xR, 0, 0, 0);
        aR = __builtin_amdgcn_mfma_f32_16x16x32_f16(Ah[0][1], Bh1, aR, 0, 0, 0);
        f32x4 aZ = __builtin_amdgcn_mfma_f32_16x16x32_f16(Ah[1][0], Bh0, xZ, 0, 0, 0);
        aZ = __builtin_amdgcn_mfma_f32_16x16x32_f16(Ah[1][1], Bh1, aZ, 0, 0, 0);
        f32x4 aH = __builtin_amdgcn_mfma_f32_16x16x32_f16(Ah[2][0], Bh0, biasH, 0, 0, 0);
        aH = __builtin_amdgcn_mfma_f32_16x16x32_f16(Ah[2][1], Bh1, aH, 0, 0, 0);
        const f32x4 aXc = xX;

        // prefetch step t+1 x-side (independent of this step's h)
        {
            const int tn = (t + 1 < TT) ? t + 1 : TT - 1;
            const int p = A.c.pb[tn][n];
            const int eidx = ((p >> sh) & mk) + of;
            half8 Bf = *(const half8*)&embl[eidx * 8];
            uint4* bu = (uint4*)&Bf;
            bu->z = isq2 ? ((unsigned)p >> 16) : bu->z;
            xR = __builtin_amdgcn_mfma_f32_16x16x32_f16(Af[0], Bf, biasR, 0, 0, 0);
            xZ = __builtin_amdgcn_mfma_f32_16x16x32_f16(Af[1], Bf, biasZ, 0, 0, 0);
            xX = __builtin_amdgcn_mfma_f32_16x16x32_f16(Af[2], Bf, biasX, 0, 0, 0);
        }

        const bool live = (t < Ln);
        _Float16 hp[4];
        #pragma unroll
        for (int e = 0; e < 4; e++) {
            // weights pre-scaled: aR,aZ in log2 domain; aX,aH in 2log2e domain
            const float r = __builtin_amdgcn_rcpf(1.f + __builtin_amdgcn_exp2f(-aR[e]));
            const float z = __builtin_amdgcn_rcpf(1.f + __builtin_amdgcn_exp2f(-aZ[e]));
            const float y2 = aXc[e] + r * aH[e];           // = 2*log2e*y
            const float nn = 1.f - 2.f * __builtin_amdgcn_rcpf(1.f + __builtin_amdgcn_exp2f(y2));
            const float hv = nn + z * (h[e] - nn);
            h[e] = live ? hv : h[e];
            hp[e] = (_Float16)h[e];
        }
        *(uint2*)&A.c.hb[buf ^ 1][n][16 * wv + 4 * q] = *(uint2*)hp;
        __syncthreads();
    }

    float4 o = make_float4(h[0], h[1], h[2], h[3]);
    *(float4*)&out[(g * 16 + n) * HID + 16 * wv + 4 * q] = o;
}

extern "C" void kernel_launch(void* const* d_in, const int* in_sizes, int n_in,
                              void* d_out, int out_size, void* d_ws, size_t ws_size,
                              hipStream_t stream) {
    const int*   actor_ids  = (const int*)d_in[0];
    const int*   action_ids = (const int*)d_in[1];
    const int*   street_ids = (const int*)d_in[2];
    const float* bet        = (const float*)d_in[3];
    const int*   vmask      = (const int*)d_in[4];
    const float* E_actor    = (const float*)d_in[5];
    const float* E_action   = (const float*)d_in[6];
    const float* E_street   = (const float*)d_in[7];
    const float* W_proj     = (const float*)d_in[8];
    const float* b_proj     = (const float*)d_in[9];
    const float* W_ih       = (const float*)d_in[10];
    const float* W_hh       = (const float*)d_in[11];
    const float* b_ih       = (const float*)d_in[12];
    const float* b_hh       = (const float*)d_in[13];
    float*       out        = (float*)d_out;

    gru_fused<<<NGRP, 256, 0, stream>>>(actor_ids, action_ids, street_ids, bet,
                                        vmask, E_actor, E_action, E_street,
                                        W_proj, b_proj, W_ih, b_ih, W_hh, b_hh,
                                        out);
}